// Round 1
// 2310.592 us; speedup vs baseline: 1.0580x; 1.0580x over previous
//
#include <hip/hip_runtime.h>
#include <hip/hip_fp16.h>
#include <math.h>

// Problem constants
#define N_ROWS 32768
#define K_CODES 8192
#define DIM 512

// Output layout (floats): quantized_st[N,D], probs[N,K], loss, perplexity
#define OUT_Q 0
#define OUT_P ((size_t)N_ROWS * DIM)                       // 16777216
#define OUT_LOSS (OUT_P + (size_t)N_ROWS * K_CODES)        // 285212672
#define OUT_PERP (OUT_LOSS + 1)

// Workspace layout (float offsets). NO contended accumulators: per-row error
// array reduced by finalize; histogram uses spread atomics only.
#define WS_WSQ 0                        // 8192 floats
#define WS_CNT (K_CODES)                // 8192 floats (histogram)
#define WS_ERR (2 * K_CODES)            // 32768 floats (per-row sq-err)
#define WS_F16 (2 * K_CODES + N_ROWS)   // 49152: f16 base (byte 196608, 16-aligned)

// f16 region layout (in _Float16 elements, relative to f16 base)
#define XH_OFF ((size_t)0)
#define XL_OFF ((size_t)N_ROWS * DIM)
#define WH_OFF ((size_t)2 * N_ROWS * DIM)
#define WL_OFF ((size_t)2 * N_ROWS * DIM + (size_t)K_CODES * DIM)
#define F16_COUNT ((size_t)2 * (N_ROWS + K_CODES) * DIM)   // 41943040 halves
#define WS_NEEDED ((size_t)WS_F16 * 4 + F16_COUNT * 2)     // ~84.1 MB

typedef _Float16 f16x8 __attribute__((ext_vector_type(8)));
typedef float f32x4 __attribute__((ext_vector_type(4)));

__device__ inline void load_lds16(const void* g, void* l) {
    __builtin_amdgcn_global_load_lds((const __attribute__((address_space(1))) void*)g,
                                     (__attribute__((address_space(3))) void*)l,
                                     16, 0, 0);
}

// Monotone float->uint key: uint order == float order (handles negatives).
__device__ inline unsigned int fkey(float f) {
    unsigned int b = __float_as_uint(f);
    return b ^ ((unsigned int)((int)b >> 31) | 0x80000000u);
}
__device__ inline float fkey_inv(unsigned int k) {
    unsigned int b = (k & 0x80000000u) ? (k ^ 0x80000000u) : ~k;
    return __uint_as_float(b);
}

// ---------------------------------------------------------------------------
// Kernel 0 (fallback path only): row squared norms for W.
// ---------------------------------------------------------------------------
__global__ void wsq_kernel(const float* __restrict__ W, float* __restrict__ ws) {
    int row = blockIdx.x;
    int lane = threadIdx.x;  // 0..63
    const float* src = W + (size_t)row * DIM;
    float4 v0 = *(const float4*)(src + lane * 8);
    float4 v1 = *(const float4*)(src + lane * 8 + 4);
    float s = v0.x * v0.x + v0.y * v0.y + v0.z * v0.z + v0.w * v0.w
            + v1.x * v1.x + v1.y * v1.y + v1.z * v1.z + v1.w * v1.w;
#pragma unroll
    for (int off = 32; off > 0; off >>= 1) s += __shfl_down(s, off, 64);
    if (lane == 0) ws[WS_WSQ + row] = s;
}

// ---------------------------------------------------------------------------
// Kernel 0b: split X and W into fp16 hi/lo pairs + fused W row norms.
// One W row = 64 consecutive 8-elem groups = exactly one wave (NX8 % 64 == 0
// and the X/W boundary is block-aligned), so a wave shuffle-reduce gives wsq.
// ---------------------------------------------------------------------------
__global__ void __launch_bounds__(256) convert_split_kernel(
    const float* __restrict__ X, const float* __restrict__ W,
    _Float16* __restrict__ f16base, float* __restrict__ ws) {
    const size_t NX8 = (size_t)N_ROWS * DIM / 8;  // 2097152
    size_t t = (size_t)blockIdx.x * 256 + threadIdx.x;
    const float* src;
    _Float16 *hd, *ld;
    bool isW = (t >= NX8);
    if (!isW) {
        src = X + t * 8;
        hd = f16base + XH_OFF + t * 8;
        ld = f16base + XL_OFF + t * 8;
    } else {
        size_t u = t - NX8;
        src = W + u * 8;
        hd = f16base + WH_OFF + u * 8;
        ld = f16base + WL_OFF + u * 8;
    }
    float4 v0 = *(const float4*)src;
    float4 v1 = *(const float4*)(src + 4);
    float v[8] = {v0.x, v0.y, v0.z, v0.w, v1.x, v1.y, v1.z, v1.w};
    f16x8 h, l;
    float s = 0.f;
#pragma unroll
    for (int i = 0; i < 8; ++i) {
        _Float16 hv = (_Float16)v[i];
        h[i] = hv;
        l[i] = (_Float16)(v[i] - (float)hv);
        s += v[i] * v[i];
    }
    *(f16x8*)hd = h;
    *(f16x8*)ld = l;
    if (isW) {  // wave-uniform branch (W region is wave-aligned)
#pragma unroll
        for (int off = 32; off > 0; off >>= 1) s += __shfl_down(s, off, 64);
        if ((threadIdx.x & 63) == 0) ws[WS_WSQ + ((t - NX8) >> 6)] = s;
    }
}

// ---------------------------------------------------------------------------
// Kernel 1 (MFMA): S[m,n] = wsq[n] - 2 * (x_m . w_n) via fp16 3-term split.
// Pipelined schedule: BM=256 x BN=128, BK=32, 512 threads (8 waves, 4x2),
// triple-buffered LDS (3 x 48 KiB), 2-deep prefetch with counted vmcnt(6)
// (never a full drain in steady state), raw s_barrier (no implicit drains),
// setprio(1) around MFMA clusters, 2 phases per K-step.
// Race audit: buffer (ks+2)%3 staged in iter ks was last READ in iter ks-1;
// the iteration-end barrier separates. vmcnt(6) at end of iter ks retires
// exactly buffer (ks+1)'s 6 loads while (ks+2)'s 6 stay in flight.
// ---------------------------------------------------------------------------
#define LDSB 24576   // halves per buffer (Ah 8192 | Al 8192 | Bh 4096 | Bl 4096)
#define AH_O 0
#define AL_O 8192
#define BH_O 16384
#define BL_O 20480

__global__ void __launch_bounds__(512, 2) gemm_dist_mfma_kernel(
    const _Float16* __restrict__ f16base, const float* __restrict__ ws,
    float* __restrict__ out) {
    __shared__ _Float16 lds[3 * LDSB];  // 144 KiB

    const int tid = threadIdx.x;
    const int w = tid >> 6;     // wave 0..7
    const int lane = tid & 63;

    // XCD-aware swizzle: nwg = 64*128 = 8192, divisible by 8 -> simple form.
    int lin = blockIdx.y * 64 + blockIdx.x;
    int swz = (lin & 7) * 1024 + (lin >> 3);
    const int bn = (swz & 63) * 128;   // code tile base   (64 tiles)
    const int bm = (swz >> 6) * 256;   // input tile base  (128 tiles)

    const int wr = w >> 1;      // m-quadrant 0..3 (64 rows each)
    const int wc = w & 1;       // n-half     0..1 (64 cols each)
    const int q = lane >> 4;    // frag k-chunk 0..3
    const int fm = lane & 15;   // frag row/col within 16
    const int l4 = lane >> 2;   // stage: row within 16-row group
    const int p = lane & 3;     // stage: chunk position

    f32x4 acc[4][4];
#pragma unroll
    for (int i = 0; i < 4; ++i)
#pragma unroll
        for (int j = 0; j < 4; ++j) acc[i][j] = (f32x4){0.f, 0.f, 0.f, 0.f};

    // Stage one K-step part into buf. part 0: A group w*2 (h+l) + Bh group w.
    // part 1: A group w*2+1 (h+l) + Bl group w.  3 loads/thread per part.
    // LDS dest wave-uniform (lane scatters +16B); global src per-lane with
    // chunk-XOR pre-swizzle (verified: 0 bank conflicts on the read side).
    auto stage = [&](int ks, _Float16* buf, int part) {
        const int kk = ks * 32;
        int g = w * 2 + part;
        int arow = g * 16 + l4;
        int ca = p ^ ((arow >> 1) & 3);
        size_t aoff = (size_t)(bm + arow) * DIM + kk + ca * 8;
        load_lds16(f16base + XH_OFF + aoff, buf + AH_O + g * 512);
        load_lds16(f16base + XL_OFF + aoff, buf + AL_O + g * 512);
        int brow = w * 16 + l4;
        int cb = p ^ ((brow >> 1) & 3);
        size_t boff = (size_t)(bn + brow) * DIM + kk + cb * 8;
        if (part == 0)
            load_lds16(f16base + WH_OFF + boff, buf + BH_O + w * 512);
        else
            load_lds16(f16base + WL_OFF + boff, buf + BL_O + w * 512);
    };

    _Float16* c0 = lds;
    _Float16* c1 = lds + LDSB;
    _Float16* c2 = lds + 2 * LDSB;

    // Prologue: stage ks0 -> c0 (6 loads), ks1 -> c1 (6 loads); wait for c0.
    stage(0, c0, 0); stage(0, c0, 1);
    stage(1, c1, 0); stage(1, c1, 1);
    asm volatile("s_waitcnt vmcnt(6)" ::: "memory");
    __builtin_amdgcn_s_barrier();
    __builtin_amdgcn_sched_barrier(0);

#pragma unroll 1
    for (int ks = 0; ks < 16; ++ks) {
        // ---- phase 1: all B frags + A(i=0,1); stage part 0 of ks+2 ----
        f16x8 bhv[4], blv[4];
#pragma unroll
        for (int j = 0; j < 4; ++j) {
            int bb = wc * 64 + j * 16 + fm;
            int off = bb * 32 + ((q ^ ((bb >> 1) & 3)) * 8);
            bhv[j] = *(const f16x8*)&c0[BH_O + off];
            blv[j] = *(const f16x8*)&c0[BL_O + off];
        }
        f16x8 ah[2], al[2];
#pragma unroll
        for (int i = 0; i < 2; ++i) {
            int am = wr * 64 + i * 16 + fm;
            int off = am * 32 + ((q ^ ((am >> 1) & 3)) * 8);
            ah[i] = *(const f16x8*)&c0[AH_O + off];
            al[i] = *(const f16x8*)&c0[AL_O + off];
        }
        if (ks < 14) stage(ks + 2, c2, 0);
        __builtin_amdgcn_s_setprio(1);
#pragma unroll
        for (int i = 0; i < 2; ++i)
#pragma unroll
            for (int j = 0; j < 4; ++j) {
                acc[i][j] = __builtin_amdgcn_mfma_f32_16x16x32_f16(
                    ah[i], bhv[j], acc[i][j], 0, 0, 0);
                acc[i][j] = __builtin_amdgcn_mfma_f32_16x16x32_f16(
                    ah[i], blv[j], acc[i][j], 0, 0, 0);
                acc[i][j] = __builtin_amdgcn_mfma_f32_16x16x32_f16(
                    al[i], bhv[j], acc[i][j], 0, 0, 0);
            }
        __builtin_amdgcn_s_setprio(0);
        __builtin_amdgcn_s_barrier();
        __builtin_amdgcn_sched_barrier(0);

        // ---- phase 2: A(i=2,3), reuse B frags; stage part 1 of ks+2 ----
#pragma unroll
        for (int i = 0; i < 2; ++i) {
            int am = wr * 64 + (i + 2) * 16 + fm;
            int off = am * 32 + ((q ^ ((am >> 1) & 3)) * 8);
            ah[i] = *(const f16x8*)&c0[AH_O + off];
            al[i] = *(const f16x8*)&c0[AL_O + off];
        }
        if (ks < 14) stage(ks + 2, c2, 1);
        __builtin_amdgcn_s_setprio(1);
#pragma unroll
        for (int i = 0; i < 2; ++i)
#pragma unroll
            for (int j = 0; j < 4; ++j) {
                acc[i + 2][j] = __builtin_amdgcn_mfma_f32_16x16x32_f16(
                    ah[i], bhv[j], acc[i + 2][j], 0, 0, 0);
                acc[i + 2][j] = __builtin_amdgcn_mfma_f32_16x16x32_f16(
                    ah[i], blv[j], acc[i + 2][j], 0, 0, 0);
                acc[i + 2][j] = __builtin_amdgcn_mfma_f32_16x16x32_f16(
                    al[i], bhv[j], acc[i + 2][j], 0, 0, 0);
            }
        __builtin_amdgcn_s_setprio(0);
        // Counted wait: retire buffer (ks+1)'s 6 loads; keep (ks+2)'s in flight.
        if (ks < 14) {
            asm volatile("s_waitcnt vmcnt(6)" ::: "memory");
        } else if (ks == 14) {
            asm volatile("s_waitcnt vmcnt(0)" ::: "memory");
        }
        __builtin_amdgcn_s_barrier();
        __builtin_amdgcn_sched_barrier(0);

        _Float16* t0 = c0; c0 = c1; c1 = c2; c2 = t0;
    }

    // Epilogue: S = wsq[n] - 2*dot (pure store).
    // C/D layout: col = lane&15, row = (lane>>4)*4 + r (m89-verified)
    const float* wsq = ws + WS_WSQ;
    float* Dout = out + OUT_P;
    const int q4 = q * 4;
#pragma unroll
    for (int i = 0; i < 4; ++i) {
#pragma unroll
        for (int j = 0; j < 4; ++j) {
            int n = bn + wc * 64 + j * 16 + fm;
            float wn = wsq[n];
#pragma unroll
            for (int r = 0; r < 4; ++r) {
                int m = bm + wr * 64 + i * 16 + q4 + r;
                Dout[(size_t)m * K_CODES + n] = wn - 2.f * acc[i][j][r];
            }
        }
    }
}

// ---------------------------------------------------------------------------
// Fallback fp32 GEMM (only if ws can't hold f16 buffers): writes S.
// ---------------------------------------------------------------------------
#define BM 128
#define BN 128
#define BK 16

__global__ void __launch_bounds__(256) gemm_dist_fp32_kernel(
    const float* __restrict__ X, const float* __restrict__ W,
    const float* __restrict__ ws, float* __restrict__ out) {
    __shared__ float As[BK][BM];
    __shared__ float Bs[BK][BN];

    const int bn = blockIdx.x * BN;
    const int bm = blockIdx.y * BM;
    const int tid = threadIdx.x;
    const int tx = tid & 15;
    const int ty = tid >> 4;
    const int lr = tid >> 1;
    const int lc = (tid & 1) * 8;

    float acc[8][8];
#pragma unroll
    for (int i = 0; i < 8; ++i)
#pragma unroll
        for (int j = 0; j < 8; ++j) acc[i][j] = 0.f;

    const float* aptr = X + (size_t)(bm + lr) * DIM + lc;
    const float* bptr = W + (size_t)(bn + lr) * DIM + lc;

    for (int k0 = 0; k0 < DIM; k0 += BK) {
        float4 a0 = *(const float4*)(aptr + k0);
        float4 a1 = *(const float4*)(aptr + k0 + 4);
        float4 b0 = *(const float4*)(bptr + k0);
        float4 b1 = *(const float4*)(bptr + k0 + 4);
        __syncthreads();
        As[lc + 0][lr] = a0.x; As[lc + 1][lr] = a0.y;
        As[lc + 2][lr] = a0.z; As[lc + 3][lr] = a0.w;
        As[lc + 4][lr] = a1.x; As[lc + 5][lr] = a1.y;
        As[lc + 6][lr] = a1.z; As[lc + 7][lr] = a1.w;
        Bs[lc + 0][lr] = b0.x; Bs[lc + 1][lr] = b0.y;
        Bs[lc + 2][lr] = b0.z; Bs[lc + 3][lr] = b0.w;
        Bs[lc + 4][lr] = b1.x; Bs[lc + 5][lr] = b1.y;
        Bs[lc + 6][lr] = b1.z; Bs[lc + 7][lr] = b1.w;
        __syncthreads();
#pragma unroll
        for (int kk = 0; kk < BK; ++kk) {
            float a[8], b[8];
            *(float4*)&a[0] = *(const float4*)&As[kk][ty * 8];
            *(float4*)&a[4] = *(const float4*)&As[kk][ty * 8 + 4];
            *(float4*)&b[0] = *(const float4*)&Bs[kk][tx * 8];
            *(float4*)&b[4] = *(const float4*)&Bs[kk][tx * 8 + 4];
#pragma unroll
            for (int i = 0; i < 8; ++i)
#pragma unroll
                for (int j = 0; j < 8; ++j)
                    acc[i][j] = fmaf(a[i], b[j], acc[i][j]);
        }
    }

    const float* wsq = ws + WS_WSQ;
    const int m0 = bm + ty * 8;
    const int n0 = bn + tx * 8;
    float wn[8];
    *(float4*)&wn[0] = *(const float4*)(wsq + n0);
    *(float4*)&wn[4] = *(const float4*)(wsq + n0 + 4);
    float* Dout = out + OUT_P;
#pragma unroll
    for (int i = 0; i < 8; ++i) {
        float4 o0, o1;
        o0.x = wn[0] - 2.f * acc[i][0];
        o0.y = wn[1] - 2.f * acc[i][1];
        o0.z = wn[2] - 2.f * acc[i][2];
        o0.w = wn[3] - 2.f * acc[i][3];
        o1.x = wn[4] - 2.f * acc[i][4];
        o1.y = wn[5] - 2.f * acc[i][5];
        o1.z = wn[6] - 2.f * acc[i][6];
        o1.w = wn[7] - 2.f * acc[i][7];
        float* drow = Dout + (size_t)(m0 + i) * K_CODES + n0;
        *(float4*)(drow) = o0;
        *(float4*)(drow + 4) = o1;
    }
}

// ---------------------------------------------------------------------------
// Kernel 2 (fused): one block per row. Register-stage the S row; packed
// (min,argmin) from registers; softmax in place; gather W[amin]; write
// quantized_st; per-row sq-err to ws (NON-atomic); spread histogram atomic.
// ---------------------------------------------------------------------------
__global__ void __launch_bounds__(256) probs_quant_kernel(
    const float* __restrict__ X, const float* __restrict__ W,
    float* __restrict__ out, float* __restrict__ ws) {
    const int n = blockIdx.x;
    const int tid = threadIdx.x;
    __shared__ unsigned long long mred[4];
    __shared__ float fred[4];

    float4* Drow4 = (float4*)(out + OUT_P + (size_t)n * K_CODES);

    // Load row into registers; packed min (key<<32 | col) on the fly.
    float4 e[8];
    unsigned long long best = ~0ull;
#pragma unroll
    for (int t = 0; t < 8; ++t) {
        float4 v = Drow4[tid + t * 256];
        e[t] = v;
        unsigned int c0 = (unsigned int)((tid + t * 256) * 4);
        unsigned long long k;
        k = ((unsigned long long)fkey(v.x) << 32) | (c0 + 0u);
        best = k < best ? k : best;
        k = ((unsigned long long)fkey(v.y) << 32) | (c0 + 1u);
        best = k < best ? k : best;
        k = ((unsigned long long)fkey(v.z) << 32) | (c0 + 2u);
        best = k < best ? k : best;
        k = ((unsigned long long)fkey(v.w) << 32) | (c0 + 3u);
        best = k < best ? k : best;
    }
#pragma unroll
    for (int d = 1; d < 64; d <<= 1) {
        unsigned long long o = __shfl_xor(best, d, 64);
        best = o < best ? o : best;
    }
    if ((tid & 63) == 0) mred[tid >> 6] = best;
    __syncthreads();
    unsigned long long bm = mred[0];
    bm = mred[1] < bm ? mred[1] : bm;
    bm = mred[2] < bm ? mred[2] : bm;
    bm = mred[3] < bm ? mred[3] : bm;
    const float smin = fkey_inv((unsigned int)(bm >> 32));
    const int amin = (int)(bm & 0xFFFFFFFFu);

    // exp(smin - s) in registers; block sum.
    float sum = 0.f;
#pragma unroll
    for (int t = 0; t < 8; ++t) {
        float4 v = e[t];
        float4 ev;
        ev.x = __expf(smin - v.x);
        ev.y = __expf(smin - v.y);
        ev.z = __expf(smin - v.z);
        ev.w = __expf(smin - v.w);
        e[t] = ev;
        sum += ev.x + ev.y + ev.z + ev.w;
    }
#pragma unroll
    for (int off = 32; off > 0; off >>= 1) sum += __shfl_down(sum, off, 64);
    if ((tid & 63) == 0) fred[tid >> 6] = sum;
    __syncthreads();
    const float inv = 1.0f / (fred[0] + fred[1] + fred[2] + fred[3]);

    // normalized store (in place)
#pragma unroll
    for (int t = 0; t < 8; ++t) {
        float4 ev = e[t];
        ev.x *= inv; ev.y *= inv; ev.z *= inv; ev.w *= inv;
        Drow4[tid + t * 256] = ev;
    }

    // quantize + straight-through + per-row error (2 floats per thread)
    const float2* xr = (const float2*)(X + (size_t)n * DIM);
    const float2* wr = (const float2*)(W + (size_t)amin * DIM);
    float2* qr = (float2*)(out + OUT_Q + (size_t)n * DIM);
    float2 x = xr[tid];
    float2 qv = wr[tid];
    float2 d2, o;
    d2.x = qv.x - x.x; d2.y = qv.y - x.y;
    o.x = x.x + d2.x;  o.y = x.y + d2.y;
    qr[tid] = o;
    float err = d2.x * d2.x + d2.y * d2.y;
#pragma unroll
    for (int off = 32; off > 0; off >>= 1) err += __shfl_down(err, off, 64);
    __syncthreads();  // WAR: everyone done reading fred before overwrite
    if ((tid & 63) == 0) fred[tid >> 6] = err;
    __syncthreads();
    if (tid == 0) {
        ws[WS_ERR + n] = fred[0] + fred[1] + fred[2] + fred[3];
        atomicAdd(ws + WS_CNT + amin, 1.0f);  // spread over 8192 addrs
    }
}

// ---------------------------------------------------------------------------
// Kernel 3: finalize loss (reduce per-row errors) + perplexity (counts).
// ---------------------------------------------------------------------------
__global__ void __launch_bounds__(1024) finalize_kernel(
    float* __restrict__ out, const float* __restrict__ ws) {
    __shared__ float red[1024];
    const int tid = threadIdx.x;

    float errsum = 0.f;
    for (int j = tid; j < N_ROWS; j += 1024) errsum += ws[WS_ERR + j];
    red[tid] = errsum;
    __syncthreads();
    for (int st = 512; st > 0; st >>= 1) {
        if (tid < st) red[tid] += red[tid + st];
        __syncthreads();
    }
    const float total_err = red[0];
    __syncthreads();

    float ent = 0.f;
    for (int j = tid; j < K_CODES; j += 1024) {
        float p = ws[WS_CNT + j] * (1.0f / (float)N_ROWS);
        ent -= p * logf(p + 1e-10f);
    }
    red[tid] = ent;
    __syncthreads();
    for (int st = 512; st > 0; st >>= 1) {
        if (tid < st) red[tid] += red[tid + st];
        __syncthreads();
    }
    if (tid == 0) {
        float mse = total_err * (1.0f / ((float)N_ROWS * (float)DIM));
        out[OUT_LOSS] = mse + 0.25f * mse;
        out[OUT_PERP] = expf(red[0]);
    }
}

// ---------------------------------------------------------------------------
extern "C" void kernel_launch(void* const* d_in, const int* in_sizes, int n_in,
                              void* d_out, int out_size, void* d_ws, size_t ws_size,
                              hipStream_t stream) {
    const float* X = (const float*)d_in[0];  // [32768, 512]
    const float* W = (const float*)d_in[1];  // [8192, 512]
    float* out = (float*)d_out;
    float* ws = (float*)d_ws;

    // zero the histogram (ws is poisoned 0xAA); WS_ERR is fully overwritten
    hipMemsetAsync(ws + WS_CNT, 0, K_CODES * sizeof(float), stream);

    if (ws_size >= WS_NEEDED) {
        _Float16* f16base = (_Float16*)(ws + WS_F16);
        const int conv_blocks =
            (int)(((size_t)(N_ROWS + K_CODES) * DIM / 8 + 255) / 256);
        // convert also computes wsq (fused W row-norms)
        convert_split_kernel<<<conv_blocks, 256, 0, stream>>>(X, W, f16base, ws);

        dim3 ggrid(64, 128);  // bn-tiles x bm-tiles
        gemm_dist_mfma_kernel<<<ggrid, 512, 0, stream>>>(f16base, ws, out);
    } else {
        wsq_kernel<<<K_CODES, 64, 0, stream>>>(W, ws);
        dim3 ggrid(K_CODES / BN, N_ROWS / BM);
        gemm_dist_fp32_kernel<<<ggrid, 256, 0, stream>>>(X, W, ws, out);
    }

    probs_quant_kernel<<<N_ROWS, 256, 0, stream>>>(X, W, out, ws);
    finalize_kernel<<<1, 1024, 0, stream>>>(out, ws);
}